// Round 13
// baseline (41.633 us; speedup 1.0000x reference)
//
#include <hip/hip_runtime.h>

#define NN   640
#define NW   20    // bitmask words per node (640/32)
#define H    64
#define MAXD 96    // degree cap; deg ~ Binomial(1279,.0187), mean 23.9

// SINGLE dispatch: block = node v, 512 threads = 8 waves. All dependencies are
// block-local (no workspace, no producer kernel, no grid sync):
//  P1: scan edge list (a==v) -> rowv bitmask in LDS (b-column loaded on hit only)
//  P2: wave-0 shfl-scan neighbor enumeration -> ulist/pre/deg
//  P3: xa rows for u in N(v) computed in-block (covers S2 since S2 subset N(v))
//  P4: second edge scan (a,b both in N(v)) -> nb[pos(a)] |= bit(b)  == N(a) cap N(v)
//  P5: pair loop, all-LDS: h = relu(xa[u] + sum_S2 xa[w] + k0 + cnt*k1)
//  P6: tail as 3 chained matvecs on raw weights: agg = hsum@W1b + deg*b1b;
//      out = relu([x_v,0]+agg @ W0a + b0a) @ W0b + b0b
__global__ __launch_bounds__(512, 6) void rnp_solo(
    const int* __restrict__ ei, int E,
    const float* __restrict__ x,
    const float* __restrict__ W1a, const float* __restrict__ b1a,
    const float* __restrict__ W1b, const float* __restrict__ b1b,
    const float* __restrict__ W0a, const float* __restrict__ b0a,
    const float* __restrict__ W0b, const float* __restrict__ b0b,
    float* __restrict__ out)
{
    __shared__ __align__(16) unsigned rowv[NW];
    __shared__ __align__(16) unsigned nb[MAXD][NW];   // N(u) ∩ N(v) per neighbor
    __shared__ float xr[MAXD][H];                     // xa rows of N(v)
    __shared__ float p1[8][H];
    __shared__ float p2[8][H];
    __shared__ float p2b[8];
    __shared__ float ash[H];
    __shared__ unsigned short ulist[MAXD];
    __shared__ int pre[NW];
    __shared__ int s_deg;

    const int v = blockIdx.x, t = threadIdx.x;
    const int lane = t & 63, wave = t >> 6;

    if (t < NW) rowv[t] = 0u;
    for (int i = t; i < MAXD * NW; i += 512) ((unsigned*)nb)[i] = 0u;
    const float xvl = x[v * H + lane];                // prefetch own x row
    __syncthreads();

    // ---- P1: build rowv (edge scan filtered a==v; b loaded on hit only) ----
    const int quads = E >> 2;
    for (int k = t; k < quads; k += 512) {
        const int4 a4 = ((const int4*)ei)[k];
        if (a4.x == v || a4.y == v || a4.z == v || a4.w == v) {
            const int4 b4 = ((const int4*)(ei + E))[k];
            if (a4.x == v && b4.x != v) atomicOr(&rowv[b4.x >> 5], 1u << (b4.x & 31));
            if (a4.y == v && b4.y != v) atomicOr(&rowv[b4.y >> 5], 1u << (b4.y & 31));
            if (a4.z == v && b4.z != v) atomicOr(&rowv[b4.z >> 5], 1u << (b4.z & 31));
            if (a4.w == v && b4.w != v) atomicOr(&rowv[b4.w >> 5], 1u << (b4.w & 31));
        }
    }
    for (int k = (quads << 2) + t; k < E; k += 512) {
        const int a = ei[k], b = ei[k + E];
        if (a == v && b != v) atomicOr(&rowv[b >> 5], 1u << (b & 31));
    }
    __syncthreads();

    // ---- P2: neighbor enumeration (wave-0 shfl-scan prefix popcount) ----
    if (wave == 0) {
        unsigned word = (lane < NW) ? rowv[lane] : 0u;
        int pc = __popc(word), scan = pc;
        #pragma unroll
        for (int off = 1; off < 32; off <<= 1) {
            int nbv = __shfl_up(scan, off, 64);
            if (lane >= off) scan += nbv;
        }
        int o = scan - pc;                            // exclusive prefix
        if (lane < NW) pre[lane] = o;
        unsigned c = word;
        while (c) {
            int b = __ffs(c) - 1; c &= c - 1;
            if (o < MAXD) ulist[o] = (unsigned short)(lane * 32 + b);
            ++o;
        }
        if (lane == NW - 1) s_deg = (o < MAXD) ? o : MAXD;
    }
    __syncthreads();
    const int deg = s_deg;

    // ---- P3: xa rows for N(v), in-block (3 matvecs/wave, 4-way ILP) ----
    for (int p = wave; p < deg; p += 8) {
        const int u = ulist[p];
        const float xu = x[u * H + lane];
        float a0 = 0, a1 = 0, a2 = 0, a3 = 0;
        #pragma unroll
        for (int k = 0; k < H; k += 4) {
            a0 += __shfl(xu, k, 64)     * W1a[k * H + lane];
            a1 += __shfl(xu, k + 1, 64) * W1a[(k + 1) * H + lane];
            a2 += __shfl(xu, k + 2, 64) * W1a[(k + 2) * H + lane];
            a3 += __shfl(xu, k + 3, 64) * W1a[(k + 3) * H + lane];
        }
        xr[p][lane] = (a0 + a1) + (a2 + a3);
    }

    // ---- P4: build nb rows (edge scan; keep edges with a,b both in N(v)) ----
    for (int k = t; k < quads; k += 512) {
        const int4 a4 = ((const int4*)ei)[k];
        const bool hx = (rowv[a4.x >> 5] >> (a4.x & 31)) & 1u;
        const bool hy = (rowv[a4.y >> 5] >> (a4.y & 31)) & 1u;
        const bool hz = (rowv[a4.z >> 5] >> (a4.z & 31)) & 1u;
        const bool hw = (rowv[a4.w >> 5] >> (a4.w & 31)) & 1u;
        if (hx || hy || hz || hw) {
            const int4 b4 = ((const int4*)(ei + E))[k];
            if (hx && a4.x != b4.x && ((rowv[b4.x >> 5] >> (b4.x & 31)) & 1u)) {
                int pos = pre[a4.x >> 5] + __popc(rowv[a4.x >> 5] & ((1u << (a4.x & 31)) - 1));
                if (pos < MAXD) atomicOr(&nb[pos][b4.x >> 5], 1u << (b4.x & 31));
            }
            if (hy && a4.y != b4.y && ((rowv[b4.y >> 5] >> (b4.y & 31)) & 1u)) {
                int pos = pre[a4.y >> 5] + __popc(rowv[a4.y >> 5] & ((1u << (a4.y & 31)) - 1));
                if (pos < MAXD) atomicOr(&nb[pos][b4.y >> 5], 1u << (b4.y & 31));
            }
            if (hz && a4.z != b4.z && ((rowv[b4.z >> 5] >> (b4.z & 31)) & 1u)) {
                int pos = pre[a4.z >> 5] + __popc(rowv[a4.z >> 5] & ((1u << (a4.z & 31)) - 1));
                if (pos < MAXD) atomicOr(&nb[pos][b4.z >> 5], 1u << (b4.z & 31));
            }
            if (hw && a4.w != b4.w && ((rowv[b4.w >> 5] >> (b4.w & 31)) & 1u)) {
                int pos = pre[a4.w >> 5] + __popc(rowv[a4.w >> 5] & ((1u << (a4.w & 31)) - 1));
                if (pos < MAXD) atomicOr(&nb[pos][b4.w >> 5], 1u << (b4.w & 31));
            }
        }
    }
    for (int k = (quads << 2) + t; k < E; k += 512) {
        const int a = ei[k], b = ei[k + E];
        if (a != b && ((rowv[a >> 5] >> (a & 31)) & 1u) && ((rowv[b >> 5] >> (b & 31)) & 1u)) {
            int pos = pre[a >> 5] + __popc(rowv[a >> 5] & ((1u << (a & 31)) - 1));
            if (pos < MAXD) atomicOr(&nb[pos][b >> 5], 1u << (b & 31));
        }
    }
    __syncthreads();

    // ---- P5: pair loop (all-LDS) ----
    const float r64v = W1a[64 * H + lane];
    const float k0 = b1a[lane] + r64v;                // b1a + 1*W1a[64]
    const float k1 = r64v + W1a[65 * H + lane];       // per-cnt term

    float hacc = 0.f;
    for (int p = wave; p < deg; p += 8) {
        const uint4* nbp = (const uint4*)nb[p];       // rows are 80B, 16B-aligned
        const uint4 q0 = nbp[0], q1 = nbp[1], q2 = nbp[2], q3 = nbp[3], q4 = nbp[4];
        unsigned cw[NW] = { q0.x, q0.y, q0.z, q0.w, q1.x, q1.y, q1.z, q1.w,
                            q2.x, q2.y, q2.z, q2.w, q3.x, q3.y, q3.z, q3.w,
                            q4.x, q4.y, q4.z, q4.w };
        int cnt = 0;
        #pragma unroll
        for (int j = 0; j < NW; ++j) cnt += __popc(cw[j]);
        float xs = 0.f;
        #pragma unroll
        for (int j = 0; j < NW; ++j) {
            unsigned c = cw[j];
            while (c) {
                int b = __ffs(c) - 1; c &= c - 1;
                int pos = pre[j] + __popc(rowv[j] & ((1u << b) - 1));
                xs += xr[pos][lane];                  // common-neighbor xa (LDS)
            }
        }
        float h = xr[p][lane] + xs + k0 + (float)cnt * k1;
        hacc += fmaxf(h, 0.f);                        // ReLU then accumulate
    }
    p1[wave][lane] = hacc;
    __syncthreads();

    // ---- P6: tail ----
    float hs = 0.f;
    #pragma unroll
    for (int w = 0; w < 8; ++w) hs += p1[w][lane];    // full hsum, every wave

    // a = hsum @ W1b + deg*b1b (65 outputs: 64 via lanes + e=64 via scalar path)
    float pa = 0.f, pa64 = 0.f;
    #pragma unroll
    for (int i = 0; i < 8; ++i) {
        const int d = wave * 8 + i;
        const float hd = __shfl(hs, d, 64);
        pa   += hd * W1b[d * 65 + lane];
        pa64 += hd * W1b[d * 65 + 64];
    }
    p2[wave][lane] = pa;
    if (lane == 0) p2b[wave] = pa64;
    __syncthreads();

    const float fdeg = (float)deg;
    float al  = fdeg * b1b[lane];
    float a64 = fdeg * b1b[64];
    #pragma unroll
    for (int w = 0; w < 8; ++w) { al += p2[w][lane]; a64 += p2b[w]; }
    if (wave == 0) ash[lane] = xvl + al;              // inp0[0..63]; inp0[64]=a64
    __syncthreads();

    // h = relu(inp0 @ W0a + b0a) — redundant per wave (LDS-broadcast reads)
    float th = b0a[lane] + a64 * W0a[64 * H + lane];
    float t0 = 0, t1 = 0, t2 = 0, t3 = 0;
    #pragma unroll
    for (int k = 0; k < H; k += 4) {
        t0 += ash[k]     * W0a[k * H + lane];
        t1 += ash[k + 1] * W0a[(k + 1) * H + lane];
        t2 += ash[k + 2] * W0a[(k + 2) * H + lane];
        t3 += ash[k + 3] * W0a[(k + 3) * H + lane];
    }
    th = fmaxf(th + (t0 + t1) + (t2 + t3), 0.f);

    // out = h @ W0b + b0b (wave 0; th identical across waves -> shfl within wave)
    if (wave == 0) {
        float o0 = 0, o1 = 0, o2 = 0, o3 = 0;
        #pragma unroll
        for (int d = 0; d < H; d += 4) {
            o0 += __shfl(th, d, 64)     * W0b[d * H + lane];
            o1 += __shfl(th, d + 1, 64) * W0b[(d + 1) * H + lane];
            o2 += __shfl(th, d + 2, 64) * W0b[(d + 2) * H + lane];
            o3 += __shfl(th, d + 3, 64) * W0b[(d + 3) * H + lane];
        }
        out[v * H + lane] = b0b[lane] + (o0 + o1) + (o2 + o3);
    }
}

extern "C" void kernel_launch(void* const* d_in, const int* in_sizes, int n_in,
                              void* d_out, int out_size, void* d_ws, size_t ws_size,
                              hipStream_t stream) {
    const float* x   = (const float*)d_in[0];
    const float* W1a = (const float*)d_in[1];
    const float* b1a = (const float*)d_in[2];
    const float* W1b = (const float*)d_in[3];
    const float* b1b = (const float*)d_in[4];
    const float* W0a = (const float*)d_in[5];
    const float* b0a = (const float*)d_in[6];
    const float* W0b = (const float*)d_in[7];
    const float* b0b = (const float*)d_in[8];
    const int*   ei  = (const int*)d_in[9];
    const int    E   = in_sizes[9] / 2;

    rnp_solo<<<NN, 512, 0, stream>>>(ei, E, x, W1a, b1a, W1b, b1b,
                                     W0a, b0a, W0b, b0b, (float*)d_out);
}

// Round 14
// 20.772 us; speedup vs baseline: 2.0044x; 2.0044x over previous
//
#include <hip/hip_runtime.h>

#define NN   640
#define NW   20    // used bitmask words per node
#define NWP  24    // padded row stride in global (96 B -> 16B-aligned rows)
#define H    64
#define MAXD 96    // degree cap; deg ~ Binomial(1279,.0187), mean 23.9

// ---------------- K1: prep ----------------
// blocks 0..159 : 4 nodes each. ALL 8 waves scan the edge list (int4 quads,
//                 3840/512 = 8 iters) into a 4-row LDS bitmask; then the 8
//                 waves each do one matvec (4 nodes x {xa, xc}).
// blocks 160..167: Wf = W1b @ W0a (8 rows/block, one row per wave)
// block  168     : bf = b1b @ W0a
__global__ __launch_bounds__(512) void prep(
    const int* __restrict__ ei, int E,
    const float* __restrict__ x,
    const float* __restrict__ W1a, const float* __restrict__ W0a,
    const float* __restrict__ W1b, const float* __restrict__ b1b,
    unsigned* __restrict__ bits, float* __restrict__ xa, float* __restrict__ xc,
    float* __restrict__ Wf, float* __restrict__ bf)
{
    const int t = threadIdx.x, lane = t & 63, wave = t >> 6, bid = blockIdx.x;

    if (bid < 160) {
        __shared__ unsigned sb[4 * NW];
        if (t < 4 * NW) sb[t] = 0u;
        __syncthreads();

        const int quads = E >> 2;
        for (int k = t; k < quads; k += 512) {          // 8 iters
            const int4 a4 = ((const int4*)ei)[k];
            if ((a4.x >> 2) == bid || (a4.y >> 2) == bid ||
                (a4.z >> 2) == bid || (a4.w >> 2) == bid) {
                const int4 b4 = ((const int4*)(ei + E))[k];
                if ((a4.x >> 2) == bid && a4.x != b4.x)
                    atomicOr(&sb[(a4.x & 3) * NW + (b4.x >> 5)], 1u << (b4.x & 31));
                if ((a4.y >> 2) == bid && a4.y != b4.y)
                    atomicOr(&sb[(a4.y & 3) * NW + (b4.y >> 5)], 1u << (b4.y & 31));
                if ((a4.z >> 2) == bid && a4.z != b4.z)
                    atomicOr(&sb[(a4.z & 3) * NW + (b4.z >> 5)], 1u << (b4.z & 31));
                if ((a4.w >> 2) == bid && a4.w != b4.w)
                    atomicOr(&sb[(a4.w & 3) * NW + (b4.w >> 5)], 1u << (b4.w & 31));
            }
        }
        for (int k = (quads << 2) + t; k < E; k += 512) {
            const int a = ei[k], b = ei[k + E];
            if ((a >> 2) == bid && a != b)
                atomicOr(&sb[(a & 3) * NW + (b >> 5)], 1u << (b & 31));
        }

        // one matvec per wave: node 4b+(w>>1), xa if (w&1)==0 else xc
        const int v = bid * 4 + (wave >> 1);
        const float* W = (wave & 1) ? W0a : W1a;
        const float xv = x[v * H + lane];
        float a0 = 0, a1 = 0, a2 = 0, a3 = 0;
        #pragma unroll
        for (int k = 0; k < H; k += 4) {
            a0 += __shfl(xv, k, 64)     * W[k * H + lane];
            a1 += __shfl(xv, k + 1, 64) * W[(k + 1) * H + lane];
            a2 += __shfl(xv, k + 2, 64) * W[(k + 2) * H + lane];
            a3 += __shfl(xv, k + 3, 64) * W[(k + 3) * H + lane];
        }
        float r = (a0 + a1) + (a2 + a3);
        if (wave & 1) xc[v * H + lane] = r; else xa[v * H + lane] = r;

        __syncthreads();
        if (t < 4 * NW) bits[(bid * 4 + t / NW) * NWP + (t % NW)] = sb[t];
    } else if (bid < 168) {
        const int d = (bid - 160) * 8 + wave;
        const float wv = W1b[d * 65 + lane];          // lane e holds W1b[d][e]
        float a0 = 0, a1 = 0, a2 = 0, a3 = 0;
        #pragma unroll
        for (int e = 0; e < 64; e += 4) {
            a0 += __shfl(wv, e, 64)     * W0a[e * H + lane];
            a1 += __shfl(wv, e + 1, 64) * W0a[(e + 1) * H + lane];
            a2 += __shfl(wv, e + 2, 64) * W0a[(e + 2) * H + lane];
            a3 += __shfl(wv, e + 3, 64) * W0a[(e + 3) * H + lane];
        }
        Wf[d * H + lane] = (a0 + a1) + (a2 + a3) + W1b[d * 65 + 64] * W0a[64 * H + lane];
    } else if (wave == 0) {
        const float bv = b1b[lane];
        float a0 = 0, a1 = 0, a2 = 0, a3 = 0;
        #pragma unroll
        for (int e = 0; e < 64; e += 4) {
            a0 += __shfl(bv, e, 64)     * W0a[e * H + lane];
            a1 += __shfl(bv, e + 1, 64) * W0a[(e + 1) * H + lane];
            a2 += __shfl(bv, e + 2, 64) * W0a[(e + 2) * H + lane];
            a3 += __shfl(bv, e + 3, 64) * W0a[(e + 3) * H + lane];
        }
        bf[lane] = (a0 + a1) + (a2 + a3) + b1b[64] * W0a[64 * H + lane];
    }
}

// ---------------- K2: fused per-node ego computation ----------------
// r9 structure + upfront flat LDS staging of ALL neighbor bit-rows, issued
// concurrently with the xr staging: one global-latency round per block, then
// the pair loop is 100% LDS-local.
__global__ __launch_bounds__(512, 6) void fused(
    const float* __restrict__ xa,  const float* __restrict__ xc,
    const float* __restrict__ W1a, const float* __restrict__ b1a,
    const float* __restrict__ Wf,  const float* __restrict__ bf,
    const float* __restrict__ b0a,
    const float* __restrict__ W0b, const float* __restrict__ b0b,
    const unsigned* __restrict__ bits,
    float* __restrict__ out)
{
    __shared__ __align__(16) unsigned rowv[NW];
    __shared__ __align__(16) unsigned nbs[MAXD * NW]; // neighbor bit-rows (80B rows)
    __shared__ float xr[MAXD][H];                     // xa rows of N(v)
    __shared__ float p1[8][H];
    __shared__ float p2[8][H];
    __shared__ unsigned short ulist[MAXD];
    __shared__ int pre[NW];
    __shared__ int s_deg;

    const int v = blockIdx.x, t = threadIdx.x;
    const int lane = t & 63, wave = t >> 6;

    if (t < NW) rowv[t] = bits[v * NWP + t];
    __syncthreads();

    // enumeration: shfl-scan prefix popcount over the 20 words
    if (wave == 0) {
        unsigned word = (lane < NW) ? rowv[lane] : 0u;
        int pc = __popc(word), scan = pc;
        #pragma unroll
        for (int off = 1; off < 32; off <<= 1) {
            int nb = __shfl_up(scan, off, 64);
            if (lane >= off) scan += nb;
        }
        int o = scan - pc;                        // exclusive prefix
        if (lane < NW) pre[lane] = o;
        unsigned c = word;
        while (c) {
            int b = __ffs(c) - 1; c &= c - 1;
            if (o < MAXD) ulist[o] = (unsigned short)(lane * 32 + b);
            ++o;
        }
        if (lane == NW - 1) s_deg = (o < MAXD) ? o : MAXD;
    }
    __syncthreads();
    const int deg = s_deg;

    // one burst of global loads: xr rows + all neighbor bit-rows
    for (int p = wave; p < deg; p += 8)
        xr[p][lane] = xa[ulist[p] * H + lane];
    for (int idx = t; idx < deg * NW; idx += 512) {
        const int p = idx / NW, w = idx - p * NW;
        nbs[p * NW + w] = bits[ulist[p] * NWP + w];
    }

    const float r64 = W1a[64 * H + lane];
    const float k0  = b1a[lane] + r64;            // b1a + 1*W1a[64]
    const float k1  = r64 + W1a[65 * H + lane];   // per-cnt term

    unsigned rw[NW];
    #pragma unroll
    for (int j = 0; j < NW; ++j) rw[j] = rowv[j];
    __syncthreads();

    float hacc = 0.f;
    for (int p = wave; p < deg; p += 8) {
        const uint4* bu = (const uint4*)(nbs + p * NW);   // 80B rows, 16B-aligned
        const uint4 q0 = bu[0], q1 = bu[1], q2 = bu[2], q3 = bu[3], q4 = bu[4];
        unsigned cw[NW] = {
            rw[0]  & q0.x, rw[1]  & q0.y, rw[2]  & q0.z, rw[3]  & q0.w,
            rw[4]  & q1.x, rw[5]  & q1.y, rw[6]  & q1.z, rw[7]  & q1.w,
            rw[8]  & q2.x, rw[9]  & q2.y, rw[10] & q2.z, rw[11] & q2.w,
            rw[12] & q3.x, rw[13] & q3.y, rw[14] & q3.z, rw[15] & q3.w,
            rw[16] & q4.x, rw[17] & q4.y, rw[18] & q4.z, rw[19] & q4.w };
        int cnt = 0;
        #pragma unroll
        for (int j = 0; j < NW; ++j) cnt += __popc(cw[j]);
        float xs = 0.f;
        #pragma unroll
        for (int j = 0; j < NW; ++j) {
            unsigned c = cw[j];
            while (c) {
                int b = __ffs(c) - 1; c &= c - 1;
                int pos = pre[j] + __popc(rw[j] & ((1u << b) - 1));
                xs += xr[pos][lane];              // common-neighbor xa from LDS
            }
        }
        float h = xr[p][lane] + xs + k0 + (float)cnt * k1;
        hacc += fmaxf(h, 0.f);                    // ReLU then accumulate
    }
    p1[wave][lane] = hacc;
    __syncthreads();

    // tail: h = relu(xc_v + hsum@Wf + deg*bf + b0a); out = h@W0b + b0b
    float hs = 0.f;
    #pragma unroll
    for (int w = 0; w < 8; ++w) hs += p1[w][lane];      // every wave: full hsum
    float s = 0.f;
    #pragma unroll
    for (int i = 0; i < 8; ++i) {
        const int d = wave * 8 + i;
        s += __shfl(hs, d, 64) * Wf[d * H + lane];
    }
    p2[wave][lane] = s;
    __syncthreads();

    float s2 = 0.f;
    #pragma unroll
    for (int w = 0; w < 8; ++w) s2 += p2[w][lane];
    const float hh = fmaxf(xc[v * H + lane] + (float)deg * bf[lane]
                           + b0a[lane] + s2, 0.f);      // full h, every wave
    float o = 0.f;
    #pragma unroll
    for (int i = 0; i < 8; ++i) {
        const int d = wave * 8 + i;
        o += __shfl(hh, d, 64) * W0b[d * H + lane];
    }
    p1[wave][lane] = o;
    __syncthreads();
    if (wave == 0) {
        float oo = b0b[lane];
        #pragma unroll
        for (int w = 0; w < 8; ++w) oo += p1[w][lane];
        out[v * H + lane] = oo;
    }
}

extern "C" void kernel_launch(void* const* d_in, const int* in_sizes, int n_in,
                              void* d_out, int out_size, void* d_ws, size_t ws_size,
                              hipStream_t stream) {
    const float* x   = (const float*)d_in[0];
    const float* W1a = (const float*)d_in[1];
    const float* b1a = (const float*)d_in[2];
    const float* W1b = (const float*)d_in[3];
    const float* b1b = (const float*)d_in[4];
    const float* W0a = (const float*)d_in[5];
    const float* b0a = (const float*)d_in[6];
    const float* W0b = (const float*)d_in[7];
    const float* b0b = (const float*)d_in[8];
    const int*   ei  = (const int*)d_in[9];
    const int    E   = in_sizes[9] / 2;

    char* ws = (char*)d_ws;
    unsigned* bits = (unsigned*)(ws);                         // 640*24*4 = 61440 B
    float*    xa   = (float*)(ws + 61440);                    // 163840 B
    float*    xc   = (float*)(ws + 61440 + 163840);           // 163840 B
    float*    Wf   = (float*)(ws + 61440 + 2 * 163840);       // 16384 B
    float*    bf   = (float*)(ws + 61440 + 2 * 163840 + 16384);

    prep<<<169, 512, 0, stream>>>(ei, E, x, W1a, W0a, W1b, b1b, bits, xa, xc, Wf, bf);
    fused<<<NN, 512, 0, stream>>>(xa, xc, W1a, b1a, Wf, bf, b0a, W0b, b0b,
                                  bits, (float*)d_out);
}